// Round 3
// baseline (1618.807 us; speedup 1.0000x reference)
//
#include <hip/hip_runtime.h>

typedef __bf16 bf16_t;
typedef __attribute__((ext_vector_type(8))) __bf16 bf16x8;
typedef __attribute__((ext_vector_type(4))) float f32x4;

#define DMODEL 512
#define SEQ 200
#define NHEAD 8
#define DH 64
#define BTOT 512
#define CHUNKB 64                   // batches per chunk
#define NCHUNK (BTOT / CHUNKB)      // 8 chunks
#define CROWS (CHUNKB * SEQ)        // 12800 rows per chunk

__device__ __forceinline__ float wave_sum(float v) {
#pragma unroll
    for (int m = 32; m >= 1; m >>= 1) v += __shfl_xor(v, m);
    return v;
}

// dual-dtype load/store: external tensors may be fp32 or bf16; flag decides.
__device__ __forceinline__ void load8f(const void* p, size_t off, int f32, float x[8]) {
    if (f32) {
        const f32x4* q = (const f32x4*)((const float*)p + off);
        f32x4 a = q[0], b = q[1];
#pragma unroll
        for (int j = 0; j < 4; ++j) { x[j] = a[j]; x[4 + j] = b[j]; }
    } else {
        bf16x8 u = *(const bf16x8*)((const bf16_t*)p + off);
#pragma unroll
        for (int j = 0; j < 8; ++j) x[j] = (float)u[j];
    }
}
__device__ __forceinline__ void store8f(void* p, size_t off, int f32, const float x[8]) {
    if (f32) {
        f32x4 a, b;
#pragma unroll
        for (int j = 0; j < 4; ++j) { a[j] = x[j]; b[j] = x[4 + j]; }
        f32x4* q = (f32x4*)((float*)p + off);
        q[0] = a; q[1] = b;
    } else {
        bf16x8 u;
#pragma unroll
        for (int j = 0; j < 8; ++j) u[j] = (__bf16)x[j];
        *(bf16x8*)((bf16_t*)p + off) = u;
    }
}
__device__ __forceinline__ float load1f(const void* p, size_t off, int f32) {
    return f32 ? ((const float*)p)[off] : (float)((const bf16_t*)p)[off];
}

// ---------- probe: read input_tensor AS bf16; garbage magnitudes => data is fp32 ----------
__global__ __launch_bounds__(256)
void probe_dtype(const void* p, int* flag)
{
    const bf16_t* b = (const bf16_t*)p;
    int tid = threadIdx.x;
    float mx = 0.f;
    for (int i = tid; i < 65536; i += 256) {
        float v = fabsf((float)b[i]);
        if (!(v == v)) v = 1e30f;           // NaN -> huge
        mx = fmaxf(mx, v);
    }
    mx = wave_sum(0.f) + mx;                // keep helper linked; real reduce below
#pragma unroll
    for (int m = 32; m >= 1; m >>= 1) mx = fmaxf(mx, __shfl_xor(mx, m));
    __shared__ float wmax[4];
    int wave = tid >> 6, lane = tid & 63;
    if (lane == 0) wmax[wave] = mx;
    __syncthreads();
    if (tid == 0) {
        float m2 = fmaxf(fmaxf(wmax[0], wmax[1]), fmaxf(wmax[2], wmax[3]));
        *flag = (m2 > 1e3f) ? 1 : 0;        // bf16 N(0,1) maxes ~6; fp32-as-bf16 ~1e38
    }
}

// ---------- transpose four 512x512 weights -> bf16 WT[z][n][k] = W[z][k][n] ----------
__global__ __launch_bounds__(256)
void transpose_w(const void* w0, const void* w1, const void* w2, const void* w3,
                 bf16_t* __restrict__ wt, const int* flagp)
{
    int f32 = *flagp;
    __shared__ bf16_t tile[32][33];
    const void* srcs[4] = {w0, w1, w2, w3};
    const void* src = srcs[blockIdx.z];
    bf16_t* dst = wt + (size_t)blockIdx.z * DMODEL * DMODEL;
    int tx = threadIdx.x, ty = threadIdx.y;   // block (32,8)
    int bx = blockIdx.x * 32, by = blockIdx.y * 32;
#pragma unroll
    for (int i = 0; i < 32; i += 8)
        tile[ty + i][tx] = (__bf16)load1f(src, (size_t)(by + ty + i) * DMODEL + bx + tx, f32);
    __syncthreads();
#pragma unroll
    for (int i = 0; i < 32; i += 8)
        dst[(size_t)(bx + ty + i) * DMODEL + by + tx] = tile[tx][ty + i];
}

// ---------- h = LayerNorm(input + pos) * g + beta ; external-dtype in, bf16 out ----------
__global__ __launch_bounds__(256)
void addln_in(const void* a, const void* c, const void* g, const void* beta,
              bf16_t* __restrict__ out, size_t base, const int* flagp)
{
    int f32 = *flagp;
    int wave = threadIdx.x >> 6, lane = threadIdx.x & 63;
    size_t row = (size_t)blockIdx.x * 4 + wave;
    size_t off = base + row * DMODEL + (size_t)lane * 8;
    float xa[8], xc[8];
    load8f(a, off, f32, xa);
    load8f(c, off, f32, xc);
    float x[8]; float s = 0.f, ss = 0.f;
#pragma unroll
    for (int j = 0; j < 8; ++j) {
        x[j] = xa[j] + xc[j];
        s += x[j]; ss += x[j] * x[j];
    }
    s = wave_sum(s); ss = wave_sum(ss);
    float mu = s * (1.f / DMODEL);
    float var = ss * (1.f / DMODEL) - mu * mu;
    float rstd = rsqrtf(var + 1e-12f);
    float vg[8], vb[8];
    load8f(g,    (size_t)lane * 8, f32, vg);
    load8f(beta, (size_t)lane * 8, f32, vb);
    bf16x8 o;
#pragma unroll
    for (int j = 0; j < 8; ++j)
        o[j] = (__bf16)((x[j] - mu) * rstd * vg[j] + vb[j]);
    *(bf16x8*)(out + row * DMODEL + (size_t)lane * 8) = o;
}

// ---------- out_final = LayerNorm(a + c) * g + beta ; bf16 in, external-dtype out ----------
__global__ __launch_bounds__(256)
void addln_out(const bf16_t* __restrict__ a, const bf16_t* __restrict__ c,
               const void* g, const void* beta, void* out, size_t obase,
               const int* flagp)
{
    int f32 = *flagp;
    int wave = threadIdx.x >> 6, lane = threadIdx.x & 63;
    size_t row = (size_t)blockIdx.x * 4 + wave;
    size_t off = row * DMODEL + (size_t)lane * 8;
    bf16x8 va = *(const bf16x8*)(a + off);
    bf16x8 vc = *(const bf16x8*)(c + off);
    float x[8]; float s = 0.f, ss = 0.f;
#pragma unroll
    for (int j = 0; j < 8; ++j) {
        x[j] = (float)va[j] + (float)vc[j];
        s += x[j]; ss += x[j] * x[j];
    }
    s = wave_sum(s); ss = wave_sum(ss);
    float mu = s * (1.f / DMODEL);
    float var = ss * (1.f / DMODEL) - mu * mu;
    float rstd = rsqrtf(var + 1e-12f);
    float vg[8], vb[8];
    load8f(g,    (size_t)lane * 8, f32, vg);
    load8f(beta, (size_t)lane * 8, f32, vb);
    float o[8];
#pragma unroll
    for (int j = 0; j < 8; ++j)
        o[j] = (x[j] - mu) * rstd * vg[j] + vb[j];
    store8f(out, obase + off, f32, o);
}

// ---------- C[M,N] = A[M,K] @ BT[N,K]^T + bias, 128x128 tile, BK=32 (bf16 internal) ----------
__global__ __launch_bounds__(256)
void gemm_bt(const bf16_t* __restrict__ A, const bf16_t* __restrict__ BT,
             const void* bias, bf16_t* __restrict__ C,
             int M, int N, int K, const int* flagp)
{
    int f32 = *flagp;
    __shared__ bf16_t As[128][56];   // +24 pad: 16B-aligned rows, 2-way banks
    __shared__ bf16_t Bs[128][56];
    int tid = threadIdx.x;
    int wave = tid >> 6, lane = tid & 63, lm = lane & 15, quad = lane >> 4;
    int m0 = blockIdx.y * 128, n0 = blockIdx.x * 128;
    int wm = (wave >> 1) * 64, wn = (wave & 1) * 64;
    int r0 = tid >> 2, c0 = (tid & 3) * 8;   // staging: 16B per thread, x2 rows

    f32x4 zero = {0.f, 0.f, 0.f, 0.f};
    f32x4 acc[4][4];
#pragma unroll
    for (int i = 0; i < 4; ++i)
#pragma unroll
        for (int j = 0; j < 4; ++j) acc[i][j] = zero;

    for (int k0 = 0; k0 < K; k0 += 32) {
        __syncthreads();
        *(bf16x8*)&As[r0][c0]      = *(const bf16x8*)&A [(size_t)(m0 + r0)      * K + k0 + c0];
        *(bf16x8*)&As[r0 + 64][c0] = *(const bf16x8*)&A [(size_t)(m0 + r0 + 64) * K + k0 + c0];
        *(bf16x8*)&Bs[r0][c0]      = *(const bf16x8*)&BT[(size_t)(n0 + r0)      * K + k0 + c0];
        *(bf16x8*)&Bs[r0 + 64][c0] = *(const bf16x8*)&BT[(size_t)(n0 + r0 + 64) * K + k0 + c0];
        __syncthreads();
        bf16x8 af[4], bfr[4];
#pragma unroll
        for (int i = 0; i < 4; ++i) af[i]  = *(const bf16x8*)&As[wm + i * 16 + lm][quad * 8];
#pragma unroll
        for (int j = 0; j < 4; ++j) bfr[j] = *(const bf16x8*)&Bs[wn + j * 16 + lm][quad * 8];
#pragma unroll
        for (int i = 0; i < 4; ++i)
#pragma unroll
            for (int j = 0; j < 4; ++j)
                acc[i][j] = __builtin_amdgcn_mfma_f32_16x16x32_bf16(af[i], bfr[j], acc[i][j], 0, 0, 0);
    }
#pragma unroll
    for (int j = 0; j < 4; ++j) {
        int col = n0 + wn + j * 16 + lm;
        float bv = load1f(bias, col, f32);
#pragma unroll
        for (int i = 0; i < 4; ++i)
#pragma unroll
            for (int r = 0; r < 4; ++r) {
                int row = m0 + wm + i * 16 + quad * 4 + r;
                C[(size_t)row * N + col] = (__bf16)(acc[i][j][r] + bv);
            }
    }
}

// ---------- ELU + per-head L2 normalize, in place, q then k (nrows rows each) ----------
__global__ __launch_bounds__(256)
void elunorm_kernel(bf16_t* __restrict__ q, bf16_t* __restrict__ k, int nrows)
{
    int wave = threadIdx.x >> 6, lane = threadIdx.x & 63;
    size_t gw = (size_t)blockIdx.x * 4 + wave;          // 0 .. 2*nrows*NHEAD
    const size_t half = (size_t)nrows * NHEAD;
    bf16_t* p = (gw >= half) ? k : q;
    size_t rh = (gw >= half) ? gw - half : gw;
    size_t row = rh >> 3; int head = (int)(rh & 7);
    size_t idx = row * DMODEL + head * DH + lane;
    float v = (float)p[idx];
    float e = v > 0.f ? v : expm1f(v);
    float ss = wave_sum(e * e);
    p[idx] = (__bf16)(e * rsqrtf(ss));
}

// ---------- kvT[bh][e][d] = sum_s kn[s,d] * v[s,e], one block per (b,h), b chunk-local ----------
__global__ __launch_bounds__(256)
void kv_kernel(const bf16_t* __restrict__ kn, const bf16_t* __restrict__ v,
               bf16_t* __restrict__ kvT)
{
    __shared__ bf16_t knT[64][232];   // [d][s], s padded to 224 with zeros
    __shared__ bf16_t vT[64][232];    // [e][s]
    int bh = blockIdx.x; int b = bh >> 3, h = bh & 7;
    int tid = threadIdx.x;
    size_t base = (size_t)b * SEQ * DMODEL + h * DH;
    for (int idx = tid; idx < SEQ * DH; idx += 256) {
        int s = idx >> 6, d = idx & 63;
        knT[d][s] = kn[base + (size_t)s * DMODEL + d];
        vT[d][s]  = v [base + (size_t)s * DMODEL + d];
    }
    for (int idx = tid; idx < 64 * 32; idx += 256) {
        int d = idx >> 5, s = SEQ + (idx & 31);
        knT[d][s] = (__bf16)0.f;
        vT[d][s]  = (__bf16)0.f;
    }
    __syncthreads();
    int wave = tid >> 6, lane = tid & 63, lm = lane & 15, quad = lane >> 4;
    int dbase = wave * 16;
    f32x4 zero = {0.f, 0.f, 0.f, 0.f};
    f32x4 acc[4];
#pragma unroll
    for (int in = 0; in < 4; ++in) acc[in] = zero;
#pragma unroll
    for (int k0 = 0; k0 < 224; k0 += 32) {
        bf16x8 a = *(const bf16x8*)&knT[dbase + lm][k0 + quad * 8];
#pragma unroll
        for (int in = 0; in < 4; ++in) {
            bf16x8 bb = *(const bf16x8*)&vT[in * 16 + lm][k0 + quad * 8];
            acc[in] = __builtin_amdgcn_mfma_f32_16x16x32_bf16(a, bb, acc[in], 0, 0, 0);
        }
    }
    bf16_t* outp = kvT + (size_t)bh * (DH * DH);
#pragma unroll
    for (int in = 0; in < 4; ++in)
#pragma unroll
        for (int r = 0; r < 4; ++r) {
            int d = dbase + quad * 4 + r;
            int e = in * 16 + lm;
            outp[e * DH + d] = (__bf16)acc[in][r];   // store transposed: [e][d]
        }
}

// ---------- ctx[s, h*64+e] = (1/8) sum_d qn[s,d] * kv[d,e], one block per (b,h) ----------
__global__ __launch_bounds__(256)
void ctx_kernel(const bf16_t* __restrict__ qn, const bf16_t* __restrict__ kvT,
                bf16_t* __restrict__ ctx)
{
    int bh = blockIdx.x; int b = bh >> 3, h = bh & 7;
    int tid = threadIdx.x;
    int wave = tid >> 6, lane = tid & 63, lm = lane & 15, quad = lane >> 4;
    const bf16_t* kvb = kvT + (size_t)bh * (DH * DH);
    bf16x8 bfr[2][4];
#pragma unroll
    for (int ks = 0; ks < 2; ++ks)
#pragma unroll
        for (int in = 0; in < 4; ++in)
            bfr[ks][in] = *(const bf16x8*)&kvb[(in * 16 + lm) * DH + ks * 32 + quad * 8];
    size_t base = (size_t)b * SEQ * DMODEL + h * DH;
    for (int mt = wave; mt < 13; mt += 4) {          // ceil(200/16)=13 tiles
        int m0 = mt * 16;
        int sA = m0 + lm; if (sA > SEQ - 1) sA = SEQ - 1;
        f32x4 zero = {0.f, 0.f, 0.f, 0.f};
        f32x4 acc[4];
#pragma unroll
        for (int in = 0; in < 4; ++in) acc[in] = zero;
#pragma unroll
        for (int ks = 0; ks < 2; ++ks) {
            bf16x8 a = *(const bf16x8*)&qn[base + (size_t)sA * DMODEL + ks * 32 + quad * 8];
#pragma unroll
            for (int in = 0; in < 4; ++in)
                acc[in] = __builtin_amdgcn_mfma_f32_16x16x32_bf16(a, bfr[ks][in], acc[in], 0, 0, 0);
        }
#pragma unroll
        for (int in = 0; in < 4; ++in)
#pragma unroll
            for (int r = 0; r < 4; ++r) {
                int s = m0 + quad * 4 + r;
                if (s < SEQ)
                    ctx[base + (size_t)s * DMODEL + in * 16 + lm] = (__bf16)(acc[in][r] * 0.125f);
            }
    }
}

extern "C" void kernel_launch(void* const* d_in, const int* in_sizes, int n_in,
                              void* d_out, int out_size, void* d_ws, size_t ws_size,
                              hipStream_t stream)
{
    const void* input = d_in[0];
    const void* pos   = d_in[1];
    // d_in[2] = attention_mask (unused by LinMHA)
    const void* Wq = d_in[3];
    const void* bq = d_in[4];
    const void* Wk = d_in[5];
    const void* bk = d_in[6];
    const void* Wv = d_in[7];
    const void* bv = d_in[8];
    const void* Wd = d_in[9];
    const void* bd = d_in[10];
    const void* g  = d_in[11];
    const void* be = d_in[12];

    // ws layout: [flag int @0, 256B reserved] then bf16 buffers (~56 MiB total)
    int* flag     = (int*)d_ws;
    bf16_t* WT    = (bf16_t*)((char*)d_ws + 256);
    bf16_t* h_c   = WT  + (size_t)4 * DMODEL * DMODEL;
    bf16_t* q_c   = h_c + (size_t)CROWS * DMODEL;
    bf16_t* k_c   = q_c + (size_t)CROWS * DMODEL;
    bf16_t* v_c   = k_c + (size_t)CROWS * DMODEL;
    bf16_t* kvT_c = v_c + (size_t)CROWS * DMODEL;

    probe_dtype<<<dim3(1), 256, 0, stream>>>(input, flag);
    transpose_w<<<dim3(16, 16, 4), dim3(32, 8), 0, stream>>>(Wq, Wk, Wv, Wd, WT, flag);

    for (int c = 0; c < NCHUNK; ++c) {
        size_t roff = (size_t)c * CROWS * DMODEL;
        addln_in<<<dim3(CROWS / 4), 256, 0, stream>>>(input, pos, g, be, h_c, roff, flag);
        gemm_bt<<<dim3(4, CROWS / 128), 256, 0, stream>>>(h_c, WT + 0 * 262144, bq, q_c, CROWS, DMODEL, DMODEL, flag);
        gemm_bt<<<dim3(4, CROWS / 128), 256, 0, stream>>>(h_c, WT + 1 * 262144, bk, k_c, CROWS, DMODEL, DMODEL, flag);
        gemm_bt<<<dim3(4, CROWS / 128), 256, 0, stream>>>(h_c, WT + 2 * 262144, bv, v_c, CROWS, DMODEL, DMODEL, flag);
        elunorm_kernel<<<dim3(2 * CROWS * NHEAD / 4), 256, 0, stream>>>(q_c, k_c, CROWS);
        kv_kernel<<<dim3(CHUNKB * NHEAD), 256, 0, stream>>>(k_c, v_c, kvT_c);
        ctx_kernel<<<dim3(CHUNKB * NHEAD), 256, 0, stream>>>(q_c, kvT_c, v_c);   // ctx -> v_c
        gemm_bt<<<dim3(4, CROWS / 128), 256, 0, stream>>>(v_c, WT + 3 * 262144, bd, k_c, CROWS, DMODEL, DMODEL, flag);
        addln_out<<<dim3(CROWS / 4), 256, 0, stream>>>(k_c, h_c, g, be, d_out, roff, flag);
    }
}